// Round 1
// baseline (816.033 us; speedup 1.0000x reference)
//
#include <hip/hip_runtime.h>
#include <math.h>

#define NRAYS 16384
#define HID 64
#define GEO 15
#define NS 128
#define NUP 128
#define STOT 256

__device__ __forceinline__ float clip1(float v){ return fminf(fmaxf(v,-1.f),1.f); }
__device__ __forceinline__ float softplusf(float x){ return fmaxf(x,0.f)+log1pf(expf(-fabsf(x))); }
__device__ __forceinline__ float sigmoidf(float x){ return 1.f/(1.f+expf(-x)); }

__device__ __forceinline__ void load_ray(const float* ro, const float* rd, int r,
    float& ox,float& oy,float& oz,float& dx,float& dy,float& dz){
  ox=ro[3*r]; oy=ro[3*r+1]; oz=ro[3*r+2];
  dx=rd[3*r]; dy=rd[3*r+1]; dz=rd[3*r+2];
  float inv = 1.f/sqrtf(dx*dx+dy*dy+dz*dz);
  dx*=inv; dy*=inv; dz*=inv;
}

__device__ __forceinline__ void aabb_nf(float ox,float oy,float oz,float dx,float dy,float dz,
    float& nears,float& fars){
  float dsx = (fabsf(dx)<1e-8f)?1e-8f:dx;
  float dsy = (fabsf(dy)<1e-8f)?1e-8f:dy;
  float dsz = (fabsf(dz)<1e-8f)?1e-8f:dz;
  float t1x=(-1.f-ox)/dsx, t2x=(1.f-ox)/dsx;
  float t1y=(-1.f-oy)/dsy, t2y=(1.f-oy)/dsy;
  float t1z=(-1.f-oz)/dsz, t2z=(1.f-oz)/dsz;
  float nr = fmaxf(fmaxf(fminf(t1x,t2x),fminf(t1y,t2y)),fminf(t1z,t2z));
  float fr = fminf(fminf(fmaxf(t1x,t2x),fmaxf(t1y,t2y)),fmaxf(t1z,t2z));
  fars  = fmaxf(fminf(fr,5.f),0.2f);
  nears = fminf(fmaxf(nr,0.2f),5.f);
}

// ---------------- kernel 1/3: density (sigma only) ----------------
// grid (NRAYS/256, 128); sample-major output sigma[i*NRAYS + r]
template<bool COARSE>
__global__ __launch_bounds__(256) void density_sigma_kernel(
    const float* __restrict__ ro, const float* __restrict__ rd,
    const float* __restrict__ W1, const float* __restrict__ b1,
    const float* __restrict__ W2, const float* __restrict__ b2,
    const float* __restrict__ zin, float* __restrict__ sigma_out)
{
  const int r = blockIdx.x*256 + threadIdx.x;
  const int i = blockIdx.y;
  float ox,oy,oz,dx,dy,dz;
  load_ray(ro,rd,r,ox,oy,oz,dx,dy,dz);
  float z;
  if (COARSE){
    float nears,fars; aabb_nf(ox,oy,oz,dx,dy,dz,nears,fars);
    float step = (fars-nears)*(1.f/127.f);
    z = nears + step*(float)i;
  } else {
    z = zin[i*NRAYS + r];
  }
  float x = clip1(ox+dx*z), y = clip1(oy+dy*z), zz = clip1(oz+dz*z);
  float o0 = b2[0];
  #pragma unroll
  for(int j=0;j<HID;j++){
    float a = b1[j];
    a = fmaf(x,  W1[j],       a);
    a = fmaf(y,  W1[HID+j],   a);
    a = fmaf(zz, W1[2*HID+j], a);
    a = fmaxf(a, 0.f);
    o0 = fmaf(a, W2[j*16], o0);
  }
  sigma_out[i*NRAYS + r] = softplusf(o0);
}

// ---------------- kernel 2: coarse composite + inverse-CDF sampling ----------------
// one thread per ray; writes new_z[k*NRAYS + r] (sample-major)
__global__ __launch_bounds__(256) void pdf_kernel(
    const float* __restrict__ ro, const float* __restrict__ rd,
    const float* __restrict__ sigma_c, float* __restrict__ new_z)
{
  const int r = blockIdx.x*256 + threadIdx.x;
  float ox,oy,oz,dx,dy,dz;
  load_ray(ro,rd,r,ox,oy,oz,dx,dy,dz);
  float nears,fars; aabb_nf(ox,oy,oz,dx,dy,dz,nears,fars);
  const float step = (fars-nears)*(1.f/127.f);

  float cdf[127];            // cdf[0..126]; temporarily holds raw weights
  float T = 1.f, wsum = 0.f;
  for(int i=0;i<127;i++){
    float sg = sigma_c[i*NRAYS + r];
    float alpha = 1.f - expf(-step*sg);
    float w = alpha*T;
    T *= (1.f - alpha + 1e-15f);
    if(i>=1){ float ww = w + 1e-5f; cdf[i] = ww; wsum += ww; }
  }
  float inv = 1.f/wsum;
  float c = 0.f;
  for(int k=1;k<127;k++){ c += cdf[k]*inv; cdf[k] = c; }
  cdf[0] = 0.f;

  const float u0 = 0.5f/128.f;
  const float du = (1.f - 1.f/128.f)/127.f;
  for(int k=0;k<NUP;k++){
    float u = u0 + du*(float)k;
    int lo=0, hi=127;
    while(lo<hi){ int mid=(lo+hi)>>1; if(cdf[mid] <= u) lo=mid+1; else hi=mid; }
    int below = max(lo-1,0), above = min(lo,126);
    float c0 = cdf[below], c1 = cdf[above];
    float bb0 = nears + step*((float)below + 0.5f);
    float bb1 = nears + step*((float)above + 0.5f);
    float den = c1 - c0; if(den < 1e-5f) den = 1.f;
    float t = (u - c0)/den;
    new_z[k*NRAYS + r] = bb0 + t*(bb1 - bb0);
  }
}

// ---------------- kernel 4: stable merge + final composite ----------------
// one thread per ray; writes ray-major z_out/w_out [r*256 + s]
__global__ __launch_bounds__(256) void merge_kernel(
    const float* __restrict__ ro, const float* __restrict__ rd,
    const float* __restrict__ sigma_c, const float* __restrict__ new_z,
    const float* __restrict__ sigma_f,
    float* __restrict__ z_out, float* __restrict__ w_out)
{
  const int r = blockIdx.x*256 + threadIdx.x;
  float ox,oy,oz,dx,dy,dz;
  load_ray(ro,rd,r,ox,oy,oz,dx,dy,dz);
  float nears,fars; aabb_nf(ox,oy,oz,dx,dy,dz,nears,fars);
  const float step  = (fars-nears)*(1.f/127.f);
  const float sdist = (fars-nears)*(1.f/128.f);

  const bool asc = (nears <= fars);
  const int di = asc ? 1 : -1;
  int ic = asc ? 0 : 127, jf = asc ? 0 : 127;
  int icu = 0, jfu = 0;
  float zc = nears + step*(float)ic;
  float sc = sigma_c[ic*NRAYS + r];
  float zf = new_z[jf*NRAYS + r];
  float sf = sigma_f[jf*NRAYS + r];

  float* zo = z_out + (size_t)r*STOT;
  float* wo = w_out + (size_t)r*STOT;

  float T = 1.f, pz = 0.f, ps = 0.f;
  for(int s=0;s<STOT;s++){
    float zn, sn;
    bool pickC = (icu < NS) && (jfu >= NUP || zc <= zf);
    if (pickC){
      zn = zc; sn = sc; icu++; ic += di;
      if (icu < NS){ zc = nears + step*(float)ic; sc = sigma_c[ic*NRAYS + r]; }
    } else {
      zn = zf; sn = sf; jfu++; jf += di;
      if (jfu < NUP){ zf = new_z[jf*NRAYS + r]; sf = sigma_f[jf*NRAYS + r]; }
    }
    if (s > 0){
      float delta = zn - pz;
      float alpha = 1.f - expf(-delta*ps);
      float w = alpha*T;
      T *= (1.f - alpha + 1e-15f);
      zo[s-1] = pz; wo[s-1] = w;
    }
    pz = zn; ps = sn;
  }
  float alpha = 1.f - expf(-sdist*ps);
  zo[STOT-1] = pz; wo[STOT-1] = alpha*T;
}

// ---------------- kernel 5: masked color MLP + accumulate ----------------
// one block (256 threads) per ray, one thread per sorted sample
__global__ __launch_bounds__(256) void render_kernel(
    const float* __restrict__ ro, const float* __restrict__ rd,
    const float* __restrict__ W1, const float* __restrict__ b1,
    const float* __restrict__ W2, const float* __restrict__ b2,
    const float* __restrict__ Wc1, const float* __restrict__ bc1,
    const float* __restrict__ Wc2, const float* __restrict__ bc2,
    const float* __restrict__ z_in, const float* __restrict__ w_in,
    float* __restrict__ out)
{
  const int r = blockIdx.x;
  const int s = threadIdx.x;
  float z = z_in[(size_t)r*STOT + s];
  float w = w_in[(size_t)r*STOT + s];

  float ox,oy,oz,dx,dy,dz;
  load_ray(ro,rd,r,ox,oy,oz,dx,dy,dz);

  float cr=0.f, cg=0.f, cb=0.f;
  if (w > 1e-4f){
    float x = clip1(ox+dx*z), y = clip1(oy+dy*z), zz = clip1(oz+dz*z);
    // density MLP -> geo (outputs 1..15)
    float o16[16];
    #pragma unroll
    for(int i=0;i<16;i++) o16[i] = b2[i];
    #pragma unroll 8
    for(int j=0;j<HID;j++){
      float a = b1[j];
      a = fmaf(x,  W1[j],       a);
      a = fmaf(y,  W1[HID+j],   a);
      a = fmaf(zz, W1[2*HID+j], a);
      a = fmaxf(a, 0.f);
      #pragma unroll
      for(int i=0;i<16;i++) o16[i] = fmaf(a, W2[j*16+i], o16[i]);
    }
    // color MLP: inp = [x,y,zz, dx,dy,dz, geo0..14]
    float a0 = bc2[0], a1 = bc2[1], a2 = bc2[2];
    #pragma unroll 8
    for(int j=0;j<HID;j++){
      float a = bc1[j];
      a = fmaf(x,  Wc1[0*HID+j], a);
      a = fmaf(y,  Wc1[1*HID+j], a);
      a = fmaf(zz, Wc1[2*HID+j], a);
      a = fmaf(dx, Wc1[3*HID+j], a);
      a = fmaf(dy, Wc1[4*HID+j], a);
      a = fmaf(dz, Wc1[5*HID+j], a);
      #pragma unroll
      for(int k=0;k<GEO;k++) a = fmaf(o16[1+k], Wc1[(6+k)*HID+j], a);
      a = fmaxf(a, 0.f);
      a0 = fmaf(a, Wc2[j*3+0], a0);
      a1 = fmaf(a, Wc2[j*3+1], a1);
      a2 = fmaf(a, Wc2[j*3+2], a2);
    }
    cr = w*sigmoidf(a0); cg = w*sigmoidf(a1); cb = w*sigmoidf(a2);
  }

  // block reduction over (cr,cg,cb,w)
  __shared__ float sred[4*4];
  int lane = s & 63, wv = s >> 6;
  #pragma unroll
  for(int off=32; off; off>>=1){
    cr += __shfl_down(cr, off, 64);
    cg += __shfl_down(cg, off, 64);
    cb += __shfl_down(cb, off, 64);
    w  += __shfl_down(w,  off, 64);
  }
  if (lane == 0){ sred[wv*4+0]=cr; sred[wv*4+1]=cg; sred[wv*4+2]=cb; sred[wv*4+3]=w; }
  __syncthreads();
  if (s == 0){
    float R=0.f,G=0.f,B=0.f,W=0.f;
    #pragma unroll
    for(int k=0;k<4;k++){ R+=sred[k*4+0]; G+=sred[k*4+1]; B+=sred[k*4+2]; W+=sred[k*4+3]; }
    float bg = 1.f - W;
    out[r*3+0] = R + bg;
    out[r*3+1] = G + bg;
    out[r*3+2] = B + bg;
  }
}

extern "C" void kernel_launch(void* const* d_in, const int* in_sizes, int n_in,
                              void* d_out, int out_size, void* d_ws, size_t ws_size,
                              hipStream_t stream) {
  const float* ro  = (const float*)d_in[0];
  const float* rd  = (const float*)d_in[1];
  const float* W1  = (const float*)d_in[2];
  const float* b1  = (const float*)d_in[3];
  const float* W2  = (const float*)d_in[4];
  const float* b2  = (const float*)d_in[5];
  const float* Wc1 = (const float*)d_in[6];
  const float* bc1 = (const float*)d_in[7];
  const float* Wc2 = (const float*)d_in[8];
  const float* bc2 = (const float*)d_in[9];
  float* out = (float*)d_out;

  float* ws = (float*)d_ws;
  float* sigma_c = ws;                                   // NRAYS*128
  float* newz    = ws + (size_t)NRAYS*NS;                // NRAYS*128
  float* sigma_f = ws + (size_t)2*NRAYS*NS;              // NRAYS*128
  float* z_srt   = ws + (size_t)3*NRAYS*NS;              // NRAYS*256
  float* w_srt   = ws + (size_t)3*NRAYS*NS + (size_t)NRAYS*STOT; // NRAYS*256

  dim3 blk(256);
  density_sigma_kernel<true><<<dim3(NRAYS/256, NS), blk, 0, stream>>>(
      ro, rd, W1, b1, W2, b2, nullptr, sigma_c);
  pdf_kernel<<<dim3(NRAYS/256), blk, 0, stream>>>(ro, rd, sigma_c, newz);
  density_sigma_kernel<false><<<dim3(NRAYS/256, NUP), blk, 0, stream>>>(
      ro, rd, W1, b1, W2, b2, newz, sigma_f);
  merge_kernel<<<dim3(NRAYS/256), blk, 0, stream>>>(
      ro, rd, sigma_c, newz, sigma_f, z_srt, w_srt);
  render_kernel<<<dim3(NRAYS), blk, 0, stream>>>(
      ro, rd, W1, b1, W2, b2, Wc1, bc1, Wc2, bc2, z_srt, w_srt, out);
}

// Round 2
// 411.296 us; speedup vs baseline: 1.9841x; 1.9841x over previous
//
#include <hip/hip_runtime.h>
#include <math.h>

#define NRAYS 16384
#define HID 64
#define GEO 15
#define NS 128
#define NUP 128
#define STOT 256

__device__ __forceinline__ float clip1(float v){ return fminf(fmaxf(v,-1.f),1.f); }
__device__ __forceinline__ float softplusf(float x){ return fmaxf(x,0.f)+log1pf(expf(-fabsf(x))); }
__device__ __forceinline__ float sigmoidf(float x){ return 1.f/(1.f+expf(-x)); }

__device__ __forceinline__ void load_ray(const float* ro, const float* rd, int r,
    float& ox,float& oy,float& oz,float& dx,float& dy,float& dz){
  ox=ro[3*r]; oy=ro[3*r+1]; oz=ro[3*r+2];
  dx=rd[3*r]; dy=rd[3*r+1]; dz=rd[3*r+2];
  float inv = 1.f/sqrtf(dx*dx+dy*dy+dz*dz);
  dx*=inv; dy*=inv; dz*=inv;
}

__device__ __forceinline__ void aabb_nf(float ox,float oy,float oz,float dx,float dy,float dz,
    float& nears,float& fars){
  float dsx = (fabsf(dx)<1e-8f)?1e-8f:dx;
  float dsy = (fabsf(dy)<1e-8f)?1e-8f:dy;
  float dsz = (fabsf(dz)<1e-8f)?1e-8f:dz;
  float t1x=(-1.f-ox)/dsx, t2x=(1.f-ox)/dsx;
  float t1y=(-1.f-oy)/dsy, t2y=(1.f-oy)/dsy;
  float t1z=(-1.f-oz)/dsz, t2z=(1.f-oz)/dsz;
  float nr = fmaxf(fmaxf(fminf(t1x,t2x),fminf(t1y,t2y)),fminf(t1z,t2z));
  float fr = fminf(fminf(fmaxf(t1x,t2x),fmaxf(t1y,t2y)),fmaxf(t1z,t2z));
  fars  = fmaxf(fminf(fr,5.f),0.2f);
  nears = fminf(fmaxf(nr,0.2f),5.f);
}

__device__ __forceinline__ float density_sigma(float x,float y,float z,
    const float* __restrict__ W1,const float* __restrict__ b1,
    const float* __restrict__ W2,const float* __restrict__ b2){
  float o0 = b2[0];
  #pragma unroll
  for(int j=0;j<HID;j++){
    float a = b1[j];
    a = fmaf(x, W1[j],       a);
    a = fmaf(y, W1[HID+j],   a);
    a = fmaf(z, W1[2*HID+j], a);
    a = fmaxf(a, 0.f);
    o0 = fmaf(a, W2[j*16], o0);
  }
  return softplusf(o0);
}

// exclusive block scan; nwaves = blockDim.x/64; lds_ws has nwaves slots.
// contains __syncthreads — all threads must call.
__device__ __forceinline__ float block_excl_scan(float v, float* lds_ws,
    int tid, int nwaves, float& total){
  float incl = v;
  #pragma unroll
  for(int off=1; off<64; off<<=1){
    float n = __shfl_up(incl, off, 64);
    if ((tid & 63) >= off) incl += n;
  }
  int wv = tid >> 6;
  if ((tid & 63) == 63) lds_ws[wv] = incl;
  __syncthreads();
  float woff = 0.f, tot = 0.f;
  for(int k=0;k<nwaves;k++){ float s = lds_ws[k]; tot += s; if (k < wv) woff += s; }
  __syncthreads();   // safe to reuse lds_ws afterwards
  total = tot;
  return woff + incl - v;
}

// ---------- kernel A: coarse density + pdf/inverse-CDF + fine density ----------
// block per ray, 128 threads. All workspace ray-major (coalesced).
__global__ __launch_bounds__(128) void coarse_pdf_fine_kernel(
    const float* __restrict__ ro, const float* __restrict__ rd,
    const float* __restrict__ W1, const float* __restrict__ b1,
    const float* __restrict__ W2, const float* __restrict__ b2,
    float* __restrict__ sigma_c, float* __restrict__ newz,
    float* __restrict__ sigma_f)
{
  const int r = blockIdx.x;
  const int i = threadIdx.x;
  __shared__ float lds_ws[2];
  __shared__ float cdf[128];

  float ox,oy,oz,dx,dy,dz;
  load_ray(ro,rd,r,ox,oy,oz,dx,dy,dz);
  float nears,fars; aabb_nf(ox,oy,oz,dx,dy,dz,nears,fars);
  const float step = (fars-nears)*(1.f/127.f);

  // coarse sigma at sample i
  float z = nears + step*(float)i;
  float sg = density_sigma(clip1(ox+dx*z), clip1(oy+dy*z), clip1(oz+dz*z), W1,b1,W2,b2);
  sigma_c[r*NS + i] = sg;

  // weights via log-space parallel scan (== cumprod(1-alpha+1e-15))
  float alpha = (i < 127) ? (1.f - expf(-step*sg)) : 0.f;
  float l     = (i < 127) ? logf(1.f - alpha + 1e-15f) : 0.f;
  float dummy;
  float S = block_excl_scan(l, lds_ws, i, 2, dummy);
  float w = alpha * expf(S);
  float ww = (i >= 1 && i < 127) ? (w + 1e-5f) : 0.f;
  float wsum;
  float c_excl = block_excl_scan(ww, lds_ws, i, 2, wsum);
  if (i < 127) cdf[i] = (c_excl + ww) / wsum;   // cdf[0]==0 since ww_0==0
  __syncthreads();

  // inverse-CDF sample k = i
  const float u0 = 0.5f/128.f;
  const float du = (1.f - 1.f/128.f)/127.f;
  float u = u0 + du*(float)i;
  int lo=0, hi=127;
  while(lo<hi){ int mid=(lo+hi)>>1; if (cdf[mid] <= u) lo=mid+1; else hi=mid; }
  int below = max(lo-1,0), above = min(lo,126);
  float c0 = cdf[below], c1 = cdf[above];
  float bb0 = nears + step*((float)below + 0.5f);
  float bb1 = nears + step*((float)above + 0.5f);
  float den = c1 - c0; if (den < 1e-5f) den = 1.f;
  float nz = bb0 + (u - c0)/den*(bb1 - bb0);
  newz[r*NUP + i] = nz;

  // fine sigma at nz (fused — no global round trip)
  float sg2 = density_sigma(clip1(ox+dx*nz), clip1(oy+dy*nz), clip1(oz+dz*nz), W1,b1,W2,b2);
  sigma_f[r*NUP + i] = sg2;
}

// ---------- kernel B: merge-path + composite + masked color MLP + reduce ----------
// block per ray, 256 threads (one per merged sample)
__global__ __launch_bounds__(256) void render_kernel(
    const float* __restrict__ ro, const float* __restrict__ rd,
    const float* __restrict__ W1, const float* __restrict__ b1,
    const float* __restrict__ W2, const float* __restrict__ b2,
    const float* __restrict__ Wc1, const float* __restrict__ bc1,
    const float* __restrict__ Wc2, const float* __restrict__ bc2,
    const float* __restrict__ sigma_c, const float* __restrict__ newz,
    const float* __restrict__ sigma_f, float* __restrict__ out)
{
  const int r = blockIdx.x;
  const int s = threadIdx.x;
  __shared__ float zA[128], zB[128];
  __shared__ float zM[257], sM[256];
  __shared__ float lds_ws[4];
  __shared__ float red[4*4];

  float ox,oy,oz,dx,dy,dz;
  load_ray(ro,rd,r,ox,oy,oz,dx,dy,dz);
  float nears,fars; aabb_nf(ox,oy,oz,dx,dy,dz,nears,fars);
  const float step  = (fars-nears)*(1.f/127.f);
  const float sdist = (fars-nears)*(1.f/128.f);
  const bool asc = (nears <= fars);

  // stage both sorted-ascending lists into LDS
  float myz, mysig;
  if (s < 128){
    int i = asc ? s : (127 - s);
    myz = nears + step*(float)i;
    mysig = sigma_c[r*NS + i];
    zA[s] = myz;
  } else {
    int k = s - 128;
    int j = asc ? k : (127 - k);
    myz = newz[r*NUP + j];
    mysig = sigma_f[r*NUP + j];
    zB[k] = myz;
  }
  __syncthreads();

  // merge path: rank = own index + rank in other list
  int pos;
  if (s < 128){
    // count of zB strictly < myz  (coarse wins ties; order irrelevant: equal z => equal sigma)
    int lo=0, hi=128;
    while(lo<hi){ int m=(lo+hi)>>1; if (zB[m] < myz) lo=m+1; else hi=m; }
    pos = s + lo;
  } else {
    // count of zA <= myz
    int lo=0, hi=128;
    while(lo<hi){ int m=(lo+hi)>>1; if (zA[m] <= myz) lo=m+1; else hi=m; }
    pos = (s - 128) + lo;
  }
  zM[pos] = myz; sM[pos] = mysig;
  __syncthreads();

  // composite via log-space scan
  float zs = zM[s], sgs = sM[s];
  float delta = (s < STOT-1) ? (zM[s+1] - zs) : sdist;
  float alpha = 1.f - expf(-delta*sgs);
  float l = logf(1.f - alpha + 1e-15f);
  float dummy;
  float S = block_excl_scan(l, lds_ws, s, 4, dummy);
  float w = alpha * expf(S);

  // masked color MLP
  float cr=0.f, cg=0.f, cb=0.f;
  if (w > 1e-4f){
    float x = clip1(ox+dx*zs), y = clip1(oy+dy*zs), zz = clip1(oz+dz*zs);
    float o16[16];
    #pragma unroll
    for(int i=0;i<16;i++) o16[i] = b2[i];
    #pragma unroll 8
    for(int j=0;j<HID;j++){
      float a = b1[j];
      a = fmaf(x,  W1[j],       a);
      a = fmaf(y,  W1[HID+j],   a);
      a = fmaf(zz, W1[2*HID+j], a);
      a = fmaxf(a, 0.f);
      #pragma unroll
      for(int i=0;i<16;i++) o16[i] = fmaf(a, W2[j*16+i], o16[i]);
    }
    float a0 = bc2[0], a1 = bc2[1], a2 = bc2[2];
    #pragma unroll 8
    for(int j=0;j<HID;j++){
      float a = bc1[j];
      a = fmaf(x,  Wc1[0*HID+j], a);
      a = fmaf(y,  Wc1[1*HID+j], a);
      a = fmaf(zz, Wc1[2*HID+j], a);
      a = fmaf(dx, Wc1[3*HID+j], a);
      a = fmaf(dy, Wc1[4*HID+j], a);
      a = fmaf(dz, Wc1[5*HID+j], a);
      #pragma unroll
      for(int k=0;k<GEO;k++) a = fmaf(o16[1+k], Wc1[(6+k)*HID+j], a);
      a = fmaxf(a, 0.f);
      a0 = fmaf(a, Wc2[j*3+0], a0);
      a1 = fmaf(a, Wc2[j*3+1], a1);
      a2 = fmaf(a, Wc2[j*3+2], a2);
    }
    cr = w*sigmoidf(a0); cg = w*sigmoidf(a1); cb = w*sigmoidf(a2);
  }

  // block reduction of (cr,cg,cb,w)
  int lane = s & 63, wv = s >> 6;
  float wr = w;
  #pragma unroll
  for(int off=32; off; off>>=1){
    cr += __shfl_down(cr, off, 64);
    cg += __shfl_down(cg, off, 64);
    cb += __shfl_down(cb, off, 64);
    wr += __shfl_down(wr, off, 64);
  }
  if (lane == 0){ red[wv*4+0]=cr; red[wv*4+1]=cg; red[wv*4+2]=cb; red[wv*4+3]=wr; }
  __syncthreads();
  if (s == 0){
    float R=0.f,G=0.f,B=0.f,W=0.f;
    #pragma unroll
    for(int k=0;k<4;k++){ R+=red[k*4+0]; G+=red[k*4+1]; B+=red[k*4+2]; W+=red[k*4+3]; }
    float bg = 1.f - W;
    out[r*3+0] = R + bg;
    out[r*3+1] = G + bg;
    out[r*3+2] = B + bg;
  }
}

extern "C" void kernel_launch(void* const* d_in, const int* in_sizes, int n_in,
                              void* d_out, int out_size, void* d_ws, size_t ws_size,
                              hipStream_t stream) {
  const float* ro  = (const float*)d_in[0];
  const float* rd  = (const float*)d_in[1];
  const float* W1  = (const float*)d_in[2];
  const float* b1  = (const float*)d_in[3];
  const float* W2  = (const float*)d_in[4];
  const float* b2  = (const float*)d_in[5];
  const float* Wc1 = (const float*)d_in[6];
  const float* bc1 = (const float*)d_in[7];
  const float* Wc2 = (const float*)d_in[8];
  const float* bc2 = (const float*)d_in[9];
  float* out = (float*)d_out;

  float* ws = (float*)d_ws;
  float* sigma_c = ws;                          // NRAYS*128, ray-major
  float* newz    = ws + (size_t)NRAYS*NS;       // NRAYS*128, ray-major
  float* sigma_f = ws + (size_t)2*NRAYS*NS;     // NRAYS*128, ray-major

  coarse_pdf_fine_kernel<<<dim3(NRAYS), dim3(128), 0, stream>>>(
      ro, rd, W1, b1, W2, b2, sigma_c, newz, sigma_f);
  render_kernel<<<dim3(NRAYS), dim3(256), 0, stream>>>(
      ro, rd, W1, b1, W2, b2, Wc1, bc1, Wc2, bc2, sigma_c, newz, sigma_f, out);
}